// Round 2
// baseline (1452.895 us; speedup 1.0000x reference)
//
#include <hip/hip_runtime.h>
#include <hip/hip_bf16.h>

typedef __bf16 bf16;
typedef __bf16 bf16x8 __attribute__((ext_vector_type(8)));
typedef float f32x4 __attribute__((ext_vector_type(4)));

#define B_SZ 32
#define T_SZ 64
#define H_SZ 512
#define V_SZ 32000
#define NWG_REC 16

__device__ __forceinline__ float sigmoidf_(float v) { return 1.0f / (1.0f + expf(-v)); }

__device__ __forceinline__ bf16x8 cvt8(const float* __restrict__ p) {
  float4 a = *(const float4*)p;
  float4 b = *(const float4*)(p + 4);
  bf16x8 o;
  o[0] = (bf16)a.x; o[1] = (bf16)a.y; o[2] = (bf16)a.z; o[3] = (bf16)a.w;
  o[4] = (bf16)b.x; o[5] = (bf16)b.y; o[6] = (bf16)b.z; o[7] = (bf16)b.w;
  return o;
}

// ---------------- init: h0 = features (f32 in), reset barrier counter ----------------
__global__ void init_k(const float* __restrict__ feat, float* __restrict__ h_f32,
                       bf16* __restrict__ h_bf16, int* __restrict__ ctr) {
  int i = blockIdx.x * blockDim.x + threadIdx.x;
  if (i < B_SZ * H_SZ) {
    float v = feat[i];
    h_f32[i] = v;
    h_bf16[i] = (bf16)v;
  }
  if (i == 0) *ctr = 0;
}

// ---------------- convert fc_w f32 -> bf16 (16.384M elems, 8/thread) ----------------
__global__ void cvt_fcw(const float* __restrict__ src, bf16* __restrict__ dst, long n) {
  long i = (long)(blockIdx.x * blockDim.x + threadIdx.x) * 8;
  if (i < n) *(bf16x8*)(dst + i) = cvt8(src + i);
}

// ---------------- extract + convert h-parts of Wz/Wr/Wh: dst[w][n][k]=W[n][512+k] ----------------
__global__ void cvt_wh(const float* __restrict__ Wz, const float* __restrict__ Wr,
                       const float* __restrict__ Wh, bf16* __restrict__ dst) {
  int i = blockIdx.x * blockDim.x + threadIdx.x;   // 98304 total
  int w = i >> 15;
  int rem = i & 32767;
  int n = rem >> 6;
  int k8 = (rem & 63) * 8;
  const float* W = (w == 0) ? Wz : (w == 1) ? Wr : Wh;
  *(bf16x8*)(dst + (long)w * 262144 + n * 512 + k8) = cvt8(W + (long)n * 1024 + 512 + k8);
}

// ---------------- 128x128 bf16-MFMA GEMM-BT: C = A @ B^T + bias (f32 out) ----------------
// AMODE: 0 = A bf16 [M,K] direct; 1 = A f32 gathered rows emb[caps[m]] (K=lda)
// BF32:  B rows f32 (convert in staging) vs bf16
template<int AMODE, bool BF32>
__global__ __launch_bounds__(256) void gemm_bt(
    const void* __restrict__ Av,
    const int* __restrict__ caps, const float* __restrict__ emb,
    const void* __restrict__ Bv, int ldb,
    const float* __restrict__ bias,
    float* __restrict__ C, long ldc,
    int K, int mtiles)
{
  __shared__ __align__(16) bf16 lA[128 * 32];
  __shared__ __align__(16) bf16 lB[128 * 32];
  const int tid  = threadIdx.x;
  const int lane = tid & 63;
  const int l15  = lane & 15;
  const int kb8  = (lane >> 4) * 8;
  const int wid  = tid >> 6;
  const int wm   = wid >> 1, wn = wid & 1;
  const int wg   = blockIdx.x;
  const int mtile = wg % mtiles, ntile = wg / mtiles;
  const int m0 = mtile * 128, n0 = ntile * 128;

  f32x4 acc[4][4] = {};

  for (int k0 = 0; k0 < K; k0 += 32) {
    #pragma unroll
    for (int j = 0; j < 2; ++j) {
      int c = j * 256 + tid;          // 0..511
      int row = c >> 2;
      int kc = (c & 3) * 8;
      bf16x8 av;
      if (AMODE == 1) av = cvt8(emb + (long)caps[m0 + row] * K + k0 + kc);
      else            av = *(const bf16x8*)((const bf16*)Av + (long)(m0 + row) * K + k0 + kc);
      *(bf16x8*)&lA[row * 32 + kc] = av;
      bf16x8 bv;
      if (BF32) bv = cvt8((const float*)Bv + (long)(n0 + row) * ldb + k0 + kc);
      else      bv = *(const bf16x8*)((const bf16*)Bv + (long)(n0 + row) * ldb + k0 + kc);
      *(bf16x8*)&lB[row * 32 + kc] = bv;
    }
    __syncthreads();
    bf16x8 af[4], bfr[4];
    #pragma unroll
    for (int mf = 0; mf < 4; ++mf)
      af[mf] = *(const bf16x8*)&lA[(wm * 64 + mf * 16 + l15) * 32 + kb8];
    #pragma unroll
    for (int nf = 0; nf < 4; ++nf)
      bfr[nf] = *(const bf16x8*)&lB[(wn * 64 + nf * 16 + l15) * 32 + kb8];
    #pragma unroll
    for (int mf = 0; mf < 4; ++mf)
      #pragma unroll
      for (int nf = 0; nf < 4; ++nf)
        acc[mf][nf] = __builtin_amdgcn_mfma_f32_16x16x32_bf16(af[mf], bfr[nf], acc[mf][nf], 0, 0, 0);
    __syncthreads();
  }

  // epilogue: D frag col = lane&15, row = (lane>>4)*4 + r
  #pragma unroll
  for (int mf = 0; mf < 4; ++mf)
    #pragma unroll
    for (int nf = 0; nf < 4; ++nf)
      #pragma unroll
      for (int r = 0; r < 4; ++r) {
        int row = m0 + wm * 64 + mf * 16 + (lane >> 4) * 4 + r;
        int col = n0 + wn * 64 + nf * 16 + l15;
        C[(long)row * ldc + col] = acc[mf][nf][r] + bias[col];
      }
}

// ---------------- persistent GRU recurrence: 16 wgs x 256 thr (64 waves) ----------------
__device__ __forceinline__ void gridbar(int* ctr, int target) {
  __syncthreads();
  if (threadIdx.x == 0) {
    __threadfence();
    __hip_atomic_fetch_add(ctr, 1, __ATOMIC_RELEASE, __HIP_MEMORY_SCOPE_AGENT);
    while (__hip_atomic_load(ctr, __ATOMIC_ACQUIRE, __HIP_MEMORY_SCOPE_AGENT) < target) {
      __builtin_amdgcn_s_sleep(2);
    }
  }
  __syncthreads();
}

__global__ __launch_bounds__(256) void gru_rec(
    const float* __restrict__ X,        // [2048][1536] z|r|h x-preactivations (bias folded)
    const bf16* __restrict__ Wzh, const bf16* __restrict__ Wrh, const bf16* __restrict__ Whh, // [512][512]
    float* __restrict__ h_f32, bf16* __restrict__ h_bf16,
    bf16* __restrict__ rh_bf16, bf16* __restrict__ hs, int* ctr)
{
  const int u    = blockIdx.x * 4 + (threadIdx.x >> 6);  // wave 0..63
  const int lane = threadIdx.x & 63;
  const int l15  = lane & 15;
  const int kb   = (lane >> 4) * 8;
  const int rq   = (lane >> 4) * 4;
  const bool isz = (u < 32);
  const int gcol = ((isz ? u : u - 32) * 16) + l15;      // output column

  // time-invariant recurrent weights held in VGPRs
  bf16x8 B1[16];
  {
    const bf16* W = isz ? Wzh : Wrh;
    #pragma unroll
    for (int kk = 0; kk < 16; ++kk)
      B1[kk] = *(const bf16x8*)(W + (long)gcol * 512 + kk * 32 + kb);
  }
  bf16x8 B2[16];
  if (isz) {
    #pragma unroll
    for (int kk = 0; kk < 16; ++kk)
      B2[kk] = *(const bf16x8*)(Whh + (long)gcol * 512 + kk * 32 + kb);
  }

  int epoch = 0;
  for (int t = 0; t < T_SZ; ++t) {
    f32x4 zacc[2];
    // ---- phase 1: z (kept in regs) and r -> rh ----
    {
      f32x4 acc[2] = {};
      #pragma unroll
      for (int kk = 0; kk < 16; ++kk) {
        bf16x8 a0 = *(const bf16x8*)(h_bf16 + l15 * 512 + kk * 32 + kb);
        bf16x8 a1 = *(const bf16x8*)(h_bf16 + (16 + l15) * 512 + kk * 32 + kb);
        acc[0] = __builtin_amdgcn_mfma_f32_16x16x32_bf16(a0, B1[kk], acc[0], 0, 0, 0);
        acc[1] = __builtin_amdgcn_mfma_f32_16x16x32_bf16(a1, B1[kk], acc[1], 0, 0, 0);
      }
      #pragma unroll
      for (int mf = 0; mf < 2; ++mf)
        #pragma unroll
        for (int r = 0; r < 4; ++r) {
          int b = mf * 16 + rq + r;
          float v = acc[mf][r] + X[(long)(b * 64 + t) * 1536 + (isz ? gcol : 512 + gcol)];
          float s = sigmoidf_(v);
          if (isz) zacc[mf][r] = s;
          else     rh_bf16[b * 512 + gcol] = (bf16)(s * h_f32[b * 512 + gcol]);
        }
    }
    ++epoch;
    gridbar(ctr, NWG_REC * epoch);

    // ---- phase 2: h_tilde + state update (z-waves only) ----
    if (isz) {
      f32x4 acc[2] = {};
      #pragma unroll
      for (int kk = 0; kk < 16; ++kk) {
        bf16x8 a0 = *(const bf16x8*)(rh_bf16 + l15 * 512 + kk * 32 + kb);
        bf16x8 a1 = *(const bf16x8*)(rh_bf16 + (16 + l15) * 512 + kk * 32 + kb);
        acc[0] = __builtin_amdgcn_mfma_f32_16x16x32_bf16(a0, B2[kk], acc[0], 0, 0, 0);
        acc[1] = __builtin_amdgcn_mfma_f32_16x16x32_bf16(a1, B2[kk], acc[1], 0, 0, 0);
      }
      #pragma unroll
      for (int mf = 0; mf < 2; ++mf)
        #pragma unroll
        for (int r = 0; r < 4; ++r) {
          int b = mf * 16 + rq + r;
          float ht = tanhf(acc[mf][r] + X[(long)(b * 64 + t) * 1536 + 1024 + gcol]);
          float z = zacc[mf][r];
          float h = h_f32[b * 512 + gcol];
          float hn = h + z * (ht - h);    // (1-z)h + z*ht
          h_f32[b * 512 + gcol] = hn;
          h_bf16[b * 512 + gcol] = (bf16)hn;
          hs[(long)(b * 64 + t) * 512 + gcol] = (bf16)hn;
        }
    }
    ++epoch;
    gridbar(ctr, NWG_REC * epoch);
  }
}

// ---------------- host ----------------
extern "C" void kernel_launch(void* const* d_in, const int* in_sizes, int n_in,
                              void* d_out, int out_size, void* d_ws, size_t ws_size,
                              hipStream_t stream) {
  const float* feat = (const float*)d_in[0];
  const int*   caps = (const int*)d_in[1];
  const float* emb  = (const float*)d_in[2];
  const float* Wz_w = (const float*)d_in[3];
  const float* Wz_b = (const float*)d_in[4];
  const float* Wr_w = (const float*)d_in[5];
  const float* Wr_b = (const float*)d_in[6];
  const float* Wh_w = (const float*)d_in[7];
  const float* Wh_b = (const float*)d_in[8];
  const float* fc_w = (const float*)d_in[9];
  const float* fc_b = (const float*)d_in[10];
  float* out = (float*)d_out;

  char* ws = (char*)d_ws;
  float* X_all   = (float*)(ws + 0);             // 2048*1536*4 = 12,582,912
  float* h_f32   = (float*)(ws + 12582912);      // 65,536
  bf16*  h_bf16  = (bf16*) (ws + 12648448);      // 32,768
  bf16*  rh_bf16 = (bf16*) (ws + 12681216);      // 32,768
  bf16*  hs      = (bf16*) (ws + 12713984);      // 2,097,152
  bf16*  Whp     = (bf16*) (ws + 14811136);      // 3*512*512*2 = 1,572,864
  int*   ctr     = (int*)  (ws + 16384000);      // 64
  bf16*  fcw16   = (bf16*) (ws + 16384064);      // 32,768,000 -> end 49,152,064
  const bool cvt_fc = (ws_size >= (size_t)49152100);

  init_k<<<dim3(64), dim3(256), 0, stream>>>(feat, h_f32, h_bf16, ctr);
  cvt_wh<<<dim3(384), dim3(256), 0, stream>>>(Wz_w, Wr_w, Wh_w, Whp);
  if (cvt_fc)
    cvt_fcw<<<dim3(8000), dim3(256), 0, stream>>>(fc_w, fcw16, (long)V_SZ * H_SZ);

  // x-projections (bias folded): X_all[m][0:512)=z, [512:1024)=r, [1024:1536)=h
  gemm_bt<1, true><<<dim3(64), dim3(256), 0, stream>>>(
      nullptr, caps, emb, Wz_w, 1024, Wz_b, X_all + 0,    1536, 512, 16);
  gemm_bt<1, true><<<dim3(64), dim3(256), 0, stream>>>(
      nullptr, caps, emb, Wr_w, 1024, Wr_b, X_all + 512,  1536, 512, 16);
  gemm_bt<1, true><<<dim3(64), dim3(256), 0, stream>>>(
      nullptr, caps, emb, Wh_w, 1024, Wh_b, X_all + 1024, 1536, 512, 16);

  gru_rec<<<dim3(NWG_REC), dim3(256), 0, stream>>>(
      X_all, Whp, Whp + 262144, Whp + 524288, h_f32, h_bf16, rh_bf16, hs, ctr);

  // logits: hs[2048,512](bf16) @ fc_w[32000,512]^T + fc_b -> f32 out
  if (cvt_fc)
    gemm_bt<0, false><<<dim3(4000), dim3(256), 0, stream>>>(
        hs, nullptr, nullptr, fcw16, 512, fc_b, out, 32000, 512, 16);
  else
    gemm_bt<0, true><<<dim3(4000), dim3(256), 0, stream>>>(
        hs, nullptr, nullptr, fc_w, 512, fc_b, out, 32000, 512, 16);
}

// Round 3
// 1106.200 us; speedup vs baseline: 1.3134x; 1.3134x over previous
//
#include <hip/hip_runtime.h>
#include <hip/hip_bf16.h>

typedef __bf16 bf16;
typedef __bf16 bf16x8 __attribute__((ext_vector_type(8)));
typedef float f32x4 __attribute__((ext_vector_type(4)));

#define B_SZ 32
#define T_SZ 64
#define H_SZ 512
#define V_SZ 32000
#define NWG_REC 8

__device__ __forceinline__ float sigmoidf_(float v) { return 1.0f / (1.0f + expf(-v)); }

__device__ __forceinline__ bf16x8 cvt8(const float* __restrict__ p) {
  float4 a = *(const float4*)p;
  float4 b = *(const float4*)(p + 4);
  bf16x8 o;
  o[0] = (bf16)a.x; o[1] = (bf16)a.y; o[2] = (bf16)a.z; o[3] = (bf16)a.w;
  o[4] = (bf16)b.x; o[5] = (bf16)b.y; o[6] = (bf16)b.z; o[7] = (bf16)b.w;
  return o;
}

// ---------------- init: h0 = features (f32 in), reset barrier counter ----------------
__global__ void init_k(const float* __restrict__ feat, float* __restrict__ h_f32,
                       bf16* __restrict__ h_bf16, int* __restrict__ ctr) {
  int i = blockIdx.x * blockDim.x + threadIdx.x;
  if (i < B_SZ * H_SZ) {
    float v = feat[i];
    h_f32[i] = v;
    h_bf16[i] = (bf16)v;
  }
  if (i == 0) *ctr = 0;
}

// ---------------- convert fc_w f32 -> bf16 ----------------
__global__ void cvt_fcw(const float* __restrict__ src, bf16* __restrict__ dst, long n) {
  long i = (long)(blockIdx.x * blockDim.x + threadIdx.x) * 8;
  if (i < n) *(bf16x8*)(dst + i) = cvt8(src + i);
}

// ---------------- extract + convert h-parts of Wz/Wr/Wh: dst[w][n][k]=W[n][512+k] ----------------
__global__ void cvt_wh(const float* __restrict__ Wz, const float* __restrict__ Wr,
                       const float* __restrict__ Wh, bf16* __restrict__ dst) {
  int i = blockIdx.x * blockDim.x + threadIdx.x;   // 98304 total
  int w = i >> 15;
  int rem = i & 32767;
  int n = rem >> 6;
  int k8 = (rem & 63) * 8;
  const float* W = (w == 0) ? Wz : (w == 1) ? Wr : Wh;
  *(bf16x8*)(dst + (long)w * 262144 + n * 512 + k8) = cvt8(W + (long)n * 1024 + 512 + k8);
}

// ---------------- 128x128 bf16-MFMA GEMM-BT: C = A @ B^T + bias (f32 out) ----------------
template<int AMODE, bool BF32>
__global__ __launch_bounds__(256) void gemm_bt(
    const void* __restrict__ Av,
    const int* __restrict__ caps, const float* __restrict__ emb,
    const void* __restrict__ Bv, int ldb,
    const float* __restrict__ bias,
    float* __restrict__ C, long ldc,
    int K, int mtiles)
{
  __shared__ __align__(16) bf16 lA[128 * 32];
  __shared__ __align__(16) bf16 lB[128 * 32];
  const int tid  = threadIdx.x;
  const int lane = tid & 63;
  const int l15  = lane & 15;
  const int kb8  = (lane >> 4) * 8;
  const int wid  = tid >> 6;
  const int wm   = wid >> 1, wn = wid & 1;
  const int wg   = blockIdx.x;
  const int mtile = wg % mtiles, ntile = wg / mtiles;
  const int m0 = mtile * 128, n0 = ntile * 128;

  f32x4 acc[4][4] = {};

  for (int k0 = 0; k0 < K; k0 += 32) {
    #pragma unroll
    for (int j = 0; j < 2; ++j) {
      int c = j * 256 + tid;          // 0..511
      int row = c >> 2;
      int kc = (c & 3) * 8;
      bf16x8 av;
      if (AMODE == 1) av = cvt8(emb + (long)caps[m0 + row] * K + k0 + kc);
      else            av = *(const bf16x8*)((const bf16*)Av + (long)(m0 + row) * K + k0 + kc);
      *(bf16x8*)&lA[row * 32 + kc] = av;
      bf16x8 bv;
      if (BF32) bv = cvt8((const float*)Bv + (long)(n0 + row) * ldb + k0 + kc);
      else      bv = *(const bf16x8*)((const bf16*)Bv + (long)(n0 + row) * ldb + k0 + kc);
      *(bf16x8*)&lB[row * 32 + kc] = bv;
    }
    __syncthreads();
    bf16x8 af[4], bfr[4];
    #pragma unroll
    for (int mf = 0; mf < 4; ++mf)
      af[mf] = *(const bf16x8*)&lA[(wm * 64 + mf * 16 + l15) * 32 + kb8];
    #pragma unroll
    for (int nf = 0; nf < 4; ++nf)
      bfr[nf] = *(const bf16x8*)&lB[(wn * 64 + nf * 16 + l15) * 32 + kb8];
    #pragma unroll
    for (int mf = 0; mf < 4; ++mf)
      #pragma unroll
      for (int nf = 0; nf < 4; ++nf)
        acc[mf][nf] = __builtin_amdgcn_mfma_f32_16x16x32_bf16(af[mf], bfr[nf], acc[mf][nf], 0, 0, 0);
    __syncthreads();
  }

  #pragma unroll
  for (int mf = 0; mf < 4; ++mf)
    #pragma unroll
    for (int nf = 0; nf < 4; ++nf)
      #pragma unroll
      for (int r = 0; r < 4; ++r) {
        int row = m0 + wm * 64 + mf * 16 + (lane >> 4) * 4 + r;
        int col = n0 + wn * 64 + nf * 16 + l15;
        C[(long)row * ldc + col] = acc[mf][nf][r] + bias[col];
      }
}

// ---------------- persistent GRU recurrence: 8 wgs x 512 thr (64 waves) ----------------
// Wave u: batch-half bh = u>>5 (rows bh*16..bh*16+15), col group c0 = (u&31)*16.
// Phase 1: z (regs) + r -> rh for (16 rows x 16 cols). Phase 2: h_tilde + blend.
__device__ __forceinline__ void gridbar(int* ctr, int target) {
  __syncthreads();
  if (threadIdx.x == 0) {
    __hip_atomic_fetch_add(ctr, 1, __ATOMIC_RELEASE, __HIP_MEMORY_SCOPE_AGENT);
    while (__hip_atomic_load(ctr, __ATOMIC_RELAXED, __HIP_MEMORY_SCOPE_AGENT) < target)
      __builtin_amdgcn_s_sleep(1);
    (void)__hip_atomic_load(ctr, __ATOMIC_ACQUIRE, __HIP_MEMORY_SCOPE_AGENT);
  }
  __syncthreads();
}

__global__ __launch_bounds__(512, 2) void gru_rec(
    const float* __restrict__ X,        // [2048][1536] z|r|h x-preactivations (bias folded)
    const bf16* __restrict__ Wzh, const bf16* __restrict__ Wrh, const bf16* __restrict__ Whh, // [512][512]
    float* __restrict__ h_f32, bf16* __restrict__ h_bf16,
    bf16* __restrict__ rh_bf16, bf16* __restrict__ hs, int* ctr)
{
  const int u    = blockIdx.x * 8 + (threadIdx.x >> 6);  // wave 0..63
  const int lane = threadIdx.x & 63;
  const int l15  = lane & 15;
  const int kb   = (lane >> 4) * 8;
  const int rq   = (lane >> 4) * 4;
  const int b0   = (u >> 5) * 16;                        // batch-half base row
  const int c0   = (u & 31) * 16;                        // column group
  const int gcol = c0 + l15;

  // time-invariant recurrent weight slices in VGPRs (col = gcol)
  bf16x8 Bz[16], Br[16], Bh[16];
  #pragma unroll
  for (int kk = 0; kk < 16; ++kk) {
    Bz[kk] = *(const bf16x8*)(Wzh + (long)gcol * 512 + kk * 32 + kb);
    Br[kk] = *(const bf16x8*)(Wrh + (long)gcol * 512 + kk * 32 + kb);
    Bh[kk] = *(const bf16x8*)(Whh + (long)gcol * 512 + kk * 32 + kb);
  }

  // X row index for this thread's 4 output rows: b = b0 + rq + r
  long xrow[4];
  #pragma unroll
  for (int r = 0; r < 4; ++r) xrow[r] = (long)(b0 + rq + r) * 64 * 1536;

  // prefetch X z/r for t=0
  float xz[4], xr[4];
  #pragma unroll
  for (int r = 0; r < 4; ++r) {
    xz[r] = X[xrow[r] + gcol];
    xr[r] = X[xrow[r] + 512 + gcol];
  }

  int epoch = 0;
  for (int t = 0; t < T_SZ; ++t) {
    // ---- phase 1: z (kept in regs) and r -> rh, for rows b0..b0+15 ----
    f32x4 zf, rf;
    {
      f32x4 ze = {}, zo = {}, re = {}, ro = {};
      #pragma unroll
      for (int kk = 0; kk < 16; kk += 2) {
        bf16x8 a0 = *(const bf16x8*)(h_bf16 + (b0 + l15) * 512 + kk * 32 + kb);
        bf16x8 a1 = *(const bf16x8*)(h_bf16 + (b0 + l15) * 512 + (kk + 1) * 32 + kb);
        ze = __builtin_amdgcn_mfma_f32_16x16x32_bf16(a0, Bz[kk], ze, 0, 0, 0);
        re = __builtin_amdgcn_mfma_f32_16x16x32_bf16(a0, Br[kk], re, 0, 0, 0);
        zo = __builtin_amdgcn_mfma_f32_16x16x32_bf16(a1, Bz[kk + 1], zo, 0, 0, 0);
        ro = __builtin_amdgcn_mfma_f32_16x16x32_bf16(a1, Br[kk + 1], ro, 0, 0, 0);
      }
      #pragma unroll
      for (int r = 0; r < 4; ++r) {
        zf[r] = sigmoidf_(ze[r] + zo[r] + xz[r]);
        rf[r] = sigmoidf_(re[r] + ro[r] + xr[r]);
      }
    }
    // prefetch for phase 2 (barrier-independent): xh and h_prev (t-1 value)
    float xh[4], hprev[4];
    #pragma unroll
    for (int r = 0; r < 4; ++r) {
      xh[r] = X[xrow[r] + t * 1536 + 1024 + gcol];
      hprev[r] = h_f32[(b0 + rq + r) * 512 + gcol];
    }
    // write rh = r * h_prev
    #pragma unroll
    for (int r = 0; r < 4; ++r)
      rh_bf16[(b0 + rq + r) * 512 + gcol] = (bf16)(rf[r] * hprev[r]);

    ++epoch;
    gridbar(ctr, NWG_REC * epoch);

    // ---- phase 2: h_tilde + blend + store ----
    {
      f32x4 he = {}, ho = {};
      #pragma unroll
      for (int kk = 0; kk < 16; kk += 2) {
        bf16x8 a0 = *(const bf16x8*)(rh_bf16 + (b0 + l15) * 512 + kk * 32 + kb);
        bf16x8 a1 = *(const bf16x8*)(rh_bf16 + (b0 + l15) * 512 + (kk + 1) * 32 + kb);
        he = __builtin_amdgcn_mfma_f32_16x16x32_bf16(a0, Bh[kk], he, 0, 0, 0);
        ho = __builtin_amdgcn_mfma_f32_16x16x32_bf16(a1, Bh[kk + 1], ho, 0, 0, 0);
      }
      #pragma unroll
      for (int r = 0; r < 4; ++r) {
        int b = b0 + rq + r;
        float ht = tanhf(he[r] + ho[r] + xh[r]);
        float hn = hprev[r] + zf[r] * (ht - hprev[r]);   // (1-z)h + z*ht
        h_f32[b * 512 + gcol] = hn;
        h_bf16[b * 512 + gcol] = (bf16)hn;
        hs[(long)(b * 64 + t) * 512 + gcol] = (bf16)hn;
      }
    }
    // prefetch X z/r for t+1 (barrier-independent)
    if (t + 1 < T_SZ) {
      #pragma unroll
      for (int r = 0; r < 4; ++r) {
        xz[r] = X[xrow[r] + (t + 1) * 1536 + gcol];
        xr[r] = X[xrow[r] + (t + 1) * 1536 + 512 + gcol];
      }
    }
    ++epoch;
    gridbar(ctr, NWG_REC * epoch);
  }
}

// ---------------- host ----------------
extern "C" void kernel_launch(void* const* d_in, const int* in_sizes, int n_in,
                              void* d_out, int out_size, void* d_ws, size_t ws_size,
                              hipStream_t stream) {
  const float* feat = (const float*)d_in[0];
  const int*   caps = (const int*)d_in[1];
  const float* emb  = (const float*)d_in[2];
  const float* Wz_w = (const float*)d_in[3];
  const float* Wz_b = (const float*)d_in[4];
  const float* Wr_w = (const float*)d_in[5];
  const float* Wr_b = (const float*)d_in[6];
  const float* Wh_w = (const float*)d_in[7];
  const float* Wh_b = (const float*)d_in[8];
  const float* fc_w = (const float*)d_in[9];
  const float* fc_b = (const float*)d_in[10];
  float* out = (float*)d_out;

  char* ws = (char*)d_ws;
  float* X_all   = (float*)(ws + 0);             // 2048*1536*4 = 12,582,912
  float* h_f32   = (float*)(ws + 12582912);      // 65,536
  bf16*  h_bf16  = (bf16*) (ws + 12648448);      // 32,768
  bf16*  rh_bf16 = (bf16*) (ws + 12681216);      // 32,768
  bf16*  hs      = (bf16*) (ws + 12713984);      // 2,097,152
  bf16*  Whp     = (bf16*) (ws + 14811136);      // 3*512*512*2 = 1,572,864
  int*   ctr     = (int*)  (ws + 16384000);      // 64
  bf16*  fcw16   = (bf16*) (ws + 16384064);      // 32,768,000 -> end 49,152,064
  const bool cvt_fc = (ws_size >= (size_t)49152100);

  init_k<<<dim3(64), dim3(256), 0, stream>>>(feat, h_f32, h_bf16, ctr);
  cvt_wh<<<dim3(384), dim3(256), 0, stream>>>(Wz_w, Wr_w, Wh_w, Whp);
  if (cvt_fc)
    cvt_fcw<<<dim3(8000), dim3(256), 0, stream>>>(fc_w, fcw16, (long)V_SZ * H_SZ);

  // x-projections (bias folded): X_all[m][0:512)=z, [512:1024)=r, [1024:1536)=h
  gemm_bt<1, true><<<dim3(64), dim3(256), 0, stream>>>(
      nullptr, caps, emb, Wz_w, 1024, Wz_b, X_all + 0,    1536, 512, 16);
  gemm_bt<1, true><<<dim3(64), dim3(256), 0, stream>>>(
      nullptr, caps, emb, Wr_w, 1024, Wr_b, X_all + 512,  1536, 512, 16);
  gemm_bt<1, true><<<dim3(64), dim3(256), 0, stream>>>(
      nullptr, caps, emb, Wh_w, 1024, Wh_b, X_all + 1024, 1536, 512, 16);

  gru_rec<<<dim3(NWG_REC), dim3(512), 0, stream>>>(
      X_all, Whp, Whp + 262144, Whp + 524288, h_f32, h_bf16, rh_bf16, hs, ctr);

  // logits: hs[2048,512](bf16) @ fc_w[32000,512]^T + fc_b -> f32 out
  if (cvt_fc)
    gemm_bt<0, false><<<dim3(4000), dim3(256), 0, stream>>>(
        hs, nullptr, nullptr, fcw16, 512, fc_b, out, 32000, 512, 16);
  else
    gemm_bt<0, true><<<dim3(4000), dim3(256), 0, stream>>>(
        hs, nullptr, nullptr, fc_w, 512, fc_b, out, 32000, 512, 16);
}

// Round 4
// 734.783 us; speedup vs baseline: 1.9773x; 1.5055x over previous
//
#include <hip/hip_runtime.h>
#include <hip/hip_bf16.h>

typedef __bf16 bf16;
typedef __bf16 bf16x8 __attribute__((ext_vector_type(8)));
typedef float f32x4 __attribute__((ext_vector_type(4)));
typedef unsigned int u32x4 __attribute__((ext_vector_type(4)));

#define B_SZ 32
#define T_SZ 64
#define H_SZ 512
#define V_SZ 32000
#define NWG_REC 8

__device__ __forceinline__ float sigmoidf_(float v) { return 1.0f / (1.0f + expf(-v)); }

__device__ __forceinline__ bf16x8 cvt8(const float* __restrict__ p) {
  float4 a = *(const float4*)p;
  float4 b = *(const float4*)(p + 4);
  bf16x8 o;
  o[0] = (bf16)a.x; o[1] = (bf16)a.y; o[2] = (bf16)a.z; o[3] = (bf16)a.w;
  o[4] = (bf16)b.x; o[5] = (bf16)b.y; o[6] = (bf16)b.z; o[7] = (bf16)b.w;
  return o;
}

// LLC-coherent (bypass L1/L2) 16B load / 2B store
__device__ __forceinline__ u32x4 llc_load8(const bf16* p) {
  u32x4 r;
  asm volatile("global_load_dwordx4 %0, %1, off sc0 sc1" : "=v"(r) : "v"(p));
  return r;  // caller must s_waitcnt vmcnt(0) before use
}
__device__ __forceinline__ void llc_store_bf16(bf16* p, float v) {
  unsigned short us = __builtin_bit_cast(unsigned short, (bf16)v);
  unsigned int w = us;
  asm volatile("global_store_short %0, %1, off sc0 sc1" :: "v"(p), "v"(w) : "memory");
}

// ---------------- init: h0 = features -> bf16 global, reset barrier counter ----------------
__global__ void init_k(const float* __restrict__ feat, bf16* __restrict__ h_g,
                       int* __restrict__ ctr) {
  int i = blockIdx.x * blockDim.x + threadIdx.x;
  if (i < B_SZ * H_SZ) h_g[i] = (bf16)feat[i];
  if (i == 0) *ctr = 0;
}

// ---------------- convert fc_w f32 -> bf16 ----------------
__global__ void cvt_fcw(const float* __restrict__ src, bf16* __restrict__ dst, long n) {
  long i = (long)(blockIdx.x * blockDim.x + threadIdx.x) * 8;
  if (i < n) *(bf16x8*)(dst + i) = cvt8(src + i);
}

// ---------------- extract + convert h-parts of Wz/Wr/Wh: dst[w][n][k]=W[n][512+k] ----------------
__global__ void cvt_wh(const float* __restrict__ Wz, const float* __restrict__ Wr,
                       const float* __restrict__ Wh, bf16* __restrict__ dst) {
  int i = blockIdx.x * blockDim.x + threadIdx.x;   // 98304 total
  int w = i >> 15;
  int rem = i & 32767;
  int n = rem >> 6;
  int k8 = (rem & 63) * 8;
  const float* W = (w == 0) ? Wz : (w == 1) ? Wr : Wh;
  *(bf16x8*)(dst + (long)w * 262144 + n * 512 + k8) = cvt8(W + (long)n * 1024 + 512 + k8);
}

// ---------------- 128x128 bf16-MFMA GEMM-BT: C = A @ B^T + bias (f32 out) ----------------
template<int AMODE, bool BF32>
__global__ __launch_bounds__(256) void gemm_bt(
    const void* __restrict__ Av,
    const int* __restrict__ caps, const float* __restrict__ emb,
    const void* __restrict__ Bv, int ldb,
    const float* __restrict__ bias,
    float* __restrict__ C, long ldc,
    int K, int mtiles)
{
  __shared__ __align__(16) bf16 lA[128 * 32];
  __shared__ __align__(16) bf16 lB[128 * 32];
  const int tid  = threadIdx.x;
  const int lane = tid & 63;
  const int l15  = lane & 15;
  const int kb8  = (lane >> 4) * 8;
  const int wid  = tid >> 6;
  const int wm   = wid >> 1, wn = wid & 1;
  const int wg   = blockIdx.x;
  const int mtile = wg % mtiles, ntile = wg / mtiles;
  const int m0 = mtile * 128, n0 = ntile * 128;

  f32x4 acc[4][4] = {};

  for (int k0 = 0; k0 < K; k0 += 32) {
    #pragma unroll
    for (int j = 0; j < 2; ++j) {
      int c = j * 256 + tid;          // 0..511
      int row = c >> 2;
      int kc = (c & 3) * 8;
      bf16x8 av;
      if (AMODE == 1) av = cvt8(emb + (long)caps[m0 + row] * K + k0 + kc);
      else            av = *(const bf16x8*)((const bf16*)Av + (long)(m0 + row) * K + k0 + kc);
      *(bf16x8*)&lA[row * 32 + kc] = av;
      bf16x8 bv;
      if (BF32) bv = cvt8((const float*)Bv + (long)(n0 + row) * ldb + k0 + kc);
      else      bv = *(const bf16x8*)((const bf16*)Bv + (long)(n0 + row) * ldb + k0 + kc);
      *(bf16x8*)&lB[row * 32 + kc] = bv;
    }
    __syncthreads();
    bf16x8 af[4], bfr[4];
    #pragma unroll
    for (int mf = 0; mf < 4; ++mf)
      af[mf] = *(const bf16x8*)&lA[(wm * 64 + mf * 16 + l15) * 32 + kb8];
    #pragma unroll
    for (int nf = 0; nf < 4; ++nf)
      bfr[nf] = *(const bf16x8*)&lB[(wn * 64 + nf * 16 + l15) * 32 + kb8];
    #pragma unroll
    for (int mf = 0; mf < 4; ++mf)
      #pragma unroll
      for (int nf = 0; nf < 4; ++nf)
        acc[mf][nf] = __builtin_amdgcn_mfma_f32_16x16x32_bf16(af[mf], bfr[nf], acc[mf][nf], 0, 0, 0);
    __syncthreads();
  }

  #pragma unroll
  for (int mf = 0; mf < 4; ++mf)
    #pragma unroll
    for (int nf = 0; nf < 4; ++nf)
      #pragma unroll
      for (int r = 0; r < 4; ++r) {
        int row = m0 + wm * 64 + mf * 16 + (lane >> 4) * 4 + r;
        int col = n0 + wn * 64 + nf * 16 + l15;
        C[(long)row * ldc + col] = acc[mf][nf][r] + bias[col];
      }
}

// ---------------- fence-free grid barrier (relaxed atomics at LLC) ----------------
__device__ __forceinline__ void gridbar(int* ctr, int target) {
  asm volatile("s_waitcnt vmcnt(0) lgkmcnt(0)" ::: "memory");  // drain this wave's stores
  __syncthreads();
  if (threadIdx.x == 0) {
    __hip_atomic_fetch_add(ctr, 1, __ATOMIC_RELAXED, __HIP_MEMORY_SCOPE_AGENT);
    while (__hip_atomic_load(ctr, __ATOMIC_RELAXED, __HIP_MEMORY_SCOPE_AGENT) < target)
      __builtin_amdgcn_s_sleep(1);
  }
  __syncthreads();
}

// ---------------- persistent GRU recurrence: 8 wgs x 512 thr (64 waves) ----------------
// Wave u: batch-half b0=(u>>5)*16, cols c0=(u&31)*16. h state (4 f32/thread) lives in regs.
// Cross-wg state (h_bf16, rh_bf16) moves via sc0+sc1 (LLC-coherent) accesses only.
__global__ __launch_bounds__(512, 2) void gru_rec(
    const float* __restrict__ X,        // [2048][1536] z|r|h x-preactivations (bias folded)
    const bf16* __restrict__ Wzh, const bf16* __restrict__ Wrh, const bf16* __restrict__ Whh, // [512][512]
    const float* __restrict__ feat,
    bf16* __restrict__ h_g, bf16* __restrict__ rh_g,
    bf16* __restrict__ hs, int* ctr)
{
  __shared__ __align__(16) char ldsb[16384];     // 16x512 bf16 tile, XOR-swizzled
  const int tid  = threadIdx.x;                  // 0..511
  const int u    = blockIdx.x * 8 + (tid >> 6);  // wave 0..63
  const int lane = tid & 63;
  const int l15  = lane & 15;
  const int kb   = (lane >> 4) * 8;
  const int rq   = (lane >> 4) * 4;
  const int b0   = (u >> 5) * 16;
  const int c0   = (u & 31) * 16;
  const int gcol = c0 + l15;

  // time-invariant recurrent weight slices, pinned in VGPRs (asm-opaque)
  u32x4 Bz[16], Br[16], Bh[16];
  #pragma unroll
  for (int kk = 0; kk < 16; ++kk) {
    Bz[kk] = *(const u32x4*)(Wzh + (long)gcol * 512 + kk * 32 + kb);
    Br[kk] = *(const u32x4*)(Wrh + (long)gcol * 512 + kk * 32 + kb);
    Bh[kk] = *(const u32x4*)(Whh + (long)gcol * 512 + kk * 32 + kb);
  }
  #pragma unroll
  for (int kk = 0; kk < 16; ++kk)
    asm volatile("" : "+v"(Bz[kk]), "+v"(Br[kk]), "+v"(Bh[kk]));

  // wave-private h state (rows b0+rq..b0+rq+3, col gcol)
  float hprev[4];
  #pragma unroll
  for (int r = 0; r < 4; ++r) hprev[r] = feat[(b0 + rq + r) * 512 + gcol];

  int xrow[4];
  #pragma unroll
  for (int r = 0; r < 4; ++r) xrow[r] = (b0 + rq + r) * 64 * 1536;

  // prefetch X z/r for t=0 (cached loads, read-only data)
  float xz[4], xr[4];
  #pragma unroll
  for (int r = 0; r < 4; ++r) {
    xz[r] = X[xrow[r] + gcol];
    xr[r] = X[xrow[r] + 512 + gcol];
  }

  // staging indices: thread covers tile bytes tid*16 (row tid>>6) and 8192+tid*16 (row +8)
  const int srow0 = tid >> 6;
  const int soff0 = (tid * 16) ^ ((srow0 & 7) << 4);
  const int soff1 = (8192 + tid * 16) ^ ((srow0 & 7) << 4);   // (row+8)&7 == row&7
  // MFMA fragment LDS offsets
  const int fbase = (l15 * 1024 + (lane >> 4) * 16) ^ ((l15 & 7) << 4);

  int epoch = 0;
  for (int t = 0; t < T_SZ; ++t) {
    // ---- phase 1: stage h tile -> LDS, compute z (regs) and r -> rh (LLC) ----
    {
      const bf16* src = h_g + b0 * 512;
      u32x4 v0 = llc_load8(src + tid * 8);
      u32x4 v1 = llc_load8(src + 4096 + tid * 8);
      asm volatile("s_waitcnt vmcnt(0)" ::: "memory");
      __builtin_amdgcn_sched_barrier(0);
      *(u32x4*)(ldsb + soff0) = v0;
      *(u32x4*)(ldsb + soff1) = v1;
    }
    __syncthreads();
    f32x4 ze = {}, re = {};
    #pragma unroll
    for (int kk = 0; kk < 16; ++kk) {
      bf16x8 a = *(const bf16x8*)(ldsb + (fbase ^ (kk * 64)));
      ze = __builtin_amdgcn_mfma_f32_16x16x32_bf16(a, __builtin_bit_cast(bf16x8, Bz[kk]), ze, 0, 0, 0);
      re = __builtin_amdgcn_mfma_f32_16x16x32_bf16(a, __builtin_bit_cast(bf16x8, Br[kk]), re, 0, 0, 0);
    }
    float xh[4];
    #pragma unroll
    for (int r = 0; r < 4; ++r) xh[r] = X[xrow[r] + t * 1536 + 1024 + gcol];
    f32x4 zf;
    #pragma unroll
    for (int r = 0; r < 4; ++r) {
      zf[r] = sigmoidf_(ze[r] + xz[r]);
      float rv = sigmoidf_(re[r] + xr[r]);
      llc_store_bf16(rh_g + (b0 + rq + r) * 512 + gcol, rv * hprev[r]);
    }
    ++epoch;
    gridbar(ctr, NWG_REC * epoch);

    // ---- phase 2: stage rh tile -> LDS, h_tilde + blend, h -> LLC, hs -> cached ----
    {
      const bf16* src = rh_g + b0 * 512;
      u32x4 v0 = llc_load8(src + tid * 8);
      u32x4 v1 = llc_load8(src + 4096 + tid * 8);
      asm volatile("s_waitcnt vmcnt(0)" ::: "memory");
      __builtin_amdgcn_sched_barrier(0);
      *(u32x4*)(ldsb + soff0) = v0;
      *(u32x4*)(ldsb + soff1) = v1;
    }
    __syncthreads();
    f32x4 he = {};
    #pragma unroll
    for (int kk = 0; kk < 16; ++kk) {
      bf16x8 a = *(const bf16x8*)(ldsb + (fbase ^ (kk * 64)));
      he = __builtin_amdgcn_mfma_f32_16x16x32_bf16(a, __builtin_bit_cast(bf16x8, Bh[kk]), he, 0, 0, 0);
    }
    if (t + 1 < T_SZ) {
      #pragma unroll
      for (int r = 0; r < 4; ++r) {
        xz[r] = X[xrow[r] + (t + 1) * 1536 + gcol];
        xr[r] = X[xrow[r] + (t + 1) * 1536 + 512 + gcol];
      }
    }
    #pragma unroll
    for (int r = 0; r < 4; ++r) {
      int b = b0 + rq + r;
      float ht = tanhf(he[r] + xh[r]);
      float hn = hprev[r] + zf[r] * (ht - hprev[r]);   // (1-z)h + z*ht
      hprev[r] = hn;
      llc_store_bf16(h_g + b * 512 + gcol, hn);
      hs[(long)(b * 64 + t) * 512 + gcol] = (bf16)hn;  // cached; read by next kernel
    }
    ++epoch;
    gridbar(ctr, NWG_REC * epoch);
  }
}

// ---------------- host ----------------
extern "C" void kernel_launch(void* const* d_in, const int* in_sizes, int n_in,
                              void* d_out, int out_size, void* d_ws, size_t ws_size,
                              hipStream_t stream) {
  const float* feat = (const float*)d_in[0];
  const int*   caps = (const int*)d_in[1];
  const float* emb  = (const float*)d_in[2];
  const float* Wz_w = (const float*)d_in[3];
  const float* Wz_b = (const float*)d_in[4];
  const float* Wr_w = (const float*)d_in[5];
  const float* Wr_b = (const float*)d_in[6];
  const float* Wh_w = (const float*)d_in[7];
  const float* Wh_b = (const float*)d_in[8];
  const float* fc_w = (const float*)d_in[9];
  const float* fc_b = (const float*)d_in[10];
  float* out = (float*)d_out;

  char* ws = (char*)d_ws;
  float* X_all = (float*)(ws + 0);              // 12,582,912
  bf16*  h_g   = (bf16*) (ws + 12582912);       // 32,768
  bf16*  rh_g  = (bf16*) (ws + 12615680);       // 32,768
  bf16*  hs    = (bf16*) (ws + 12648448);       // 2,097,152
  bf16*  Whp   = (bf16*) (ws + 14745600);       // 1,572,864
  int*   ctr   = (int*)  (ws + 16318464);       // 64
  bf16*  fcw16 = (bf16*) (ws + 16318528);       // 32,768,000 -> end 49,086,528
  const bool cvt_fc = (ws_size >= (size_t)49086600);

  init_k<<<dim3(64), dim3(256), 0, stream>>>(feat, h_g, ctr);
  cvt_wh<<<dim3(384), dim3(256), 0, stream>>>(Wz_w, Wr_w, Wh_w, Whp);
  if (cvt_fc)
    cvt_fcw<<<dim3(8000), dim3(256), 0, stream>>>(fc_w, fcw16, (long)V_SZ * H_SZ);

  // x-projections (bias folded): X_all[m][0:512)=z, [512:1024)=r, [1024:1536)=h
  gemm_bt<1, true><<<dim3(64), dim3(256), 0, stream>>>(
      nullptr, caps, emb, Wz_w, 1024, Wz_b, X_all + 0,    1536, 512, 16);
  gemm_bt<1, true><<<dim3(64), dim3(256), 0, stream>>>(
      nullptr, caps, emb, Wr_w, 1024, Wr_b, X_all + 512,  1536, 512, 16);
  gemm_bt<1, true><<<dim3(64), dim3(256), 0, stream>>>(
      nullptr, caps, emb, Wh_w, 1024, Wh_b, X_all + 1024, 1536, 512, 16);

  gru_rec<<<dim3(NWG_REC), dim3(512), 0, stream>>>(
      X_all, Whp, Whp + 262144, Whp + 524288, feat, h_g, rh_g, hs, ctr);

  // logits: hs[2048,512](bf16) @ fc_w[32000,512]^T + fc_b -> f32 out
  if (cvt_fc)
    gemm_bt<0, false><<<dim3(4000), dim3(256), 0, stream>>>(
        hs, nullptr, nullptr, fcw16, 512, fc_b, out, 32000, 512, 16);
  else
    gemm_bt<0, true><<<dim3(4000), dim3(256), 0, stream>>>(
        hs, nullptr, nullptr, fc_w, 512, fc_b, out, 32000, 512, 16);
}